// Round 6
// baseline (229.040 us; speedup 1.0000x reference)
//
#include <hip/hip_runtime.h>
#include <hip/hip_bf16.h>
#include <cstdint>

// Problem (all inputs/outputs fp32):
//   out[8192][2048] = X[8192][2048] @ Weff[2048][2048]
//   Weff[k][n] = W[k][n] + SCALE * sum_r A[k][r]*Bk[r][n], SCALE = 4/4 = 1.0
//
// Pipeline (2 launches):
//   prep_wt  : fp32 (W + A@Bk)^T -> bf16 Wt [N][K] in d_ws (8 MB)
//   gemm_xf32: 128x128 tile, BK=64, mfma_f32_16x16x32_bf16.
//     A-tile: fused fp32->bf16 staging (float4 loads, VALU cvt, swizzled
//             ds_write_b64) — no separate cvt pass.
//     B-tile: global_load_lds width=16, XOR-chunk swizzle p = c ^ (row&7)
//             (SQ_LDS_BANK_CONFLICT = 0, verified R3/R5).
//     XCD patch swizzle (verified R5: FETCH 139->80 MB): lid&7 -> XCD owns
//             8 M-blocks x all 16 N-blocks; whole patch co-resident (4 blk/CU)
//             so the 16x N-re-reads of fp32 X are served by L2/LLC, not HBM.
//   R4 lesson: fused fp32-A WITHOUT the patch swizzle amplifies X HBM traffic
//             (FETCH 266 MB, HBM-bound, 134 us). The swizzle is the fix.

using bf16 = __hip_bfloat16;
typedef __attribute__((ext_vector_type(8))) __bf16 bf16x8;
typedef __attribute__((ext_vector_type(4))) float f32x4;

constexpr int Mdim = 8192;   // B*S
constexpr int Ndim = 2048;   // NH*HD
constexpr int Kdim = 2048;   // H
constexpr float SCALE = 1.0f;  // ALPHA/RANK = 4/4

constexpr int BM = 128, BN = 128, BK = 64;

__device__ __forceinline__ void gload_lds16(const void* g, void* l) {
  __builtin_amdgcn_global_load_lds(
      (const __attribute__((address_space(1))) uint32_t*)g,
      (__attribute__((address_space(3))) uint32_t*)l,
      16, 0, 0);
}

// ---------------- prep: Weff^T = (W + A@Bk)^T, [N][K] bf16 ----------------
__global__ void prep_wt(const float* __restrict__ W, const float* __restrict__ A,
                        const float* __restrict__ Bk, uint16_t* __restrict__ Wt) {
  __shared__ float tile[64][65];  // [n_local][k_local], +1 pad kills conflicts
  const int tx = threadIdx.x & 63;   // along N on load, along K on store
  const int ty = threadIdx.x >> 6;   // 0..3
  const int n0 = blockIdx.x * 64, k0 = blockIdx.y * 64;

  const int n = n0 + tx;
  const float b0 = Bk[0 * Ndim + n];
  const float b1 = Bk[1 * Ndim + n];
  const float b2 = Bk[2 * Ndim + n];
  const float b3 = Bk[3 * Ndim + n];

  for (int i = ty; i < 64; i += 4) {
    const int k = k0 + i;
    float w = W[(size_t)k * Ndim + n];
    w += SCALE * (A[k * 4 + 0] * b0 + A[k * 4 + 1] * b1 +
                  A[k * 4 + 2] * b2 + A[k * 4 + 3] * b3);
    tile[tx][i] = w;                       // transposed into LDS
  }
  __syncthreads();
  for (int i = ty; i < 64; i += 4) {
    Wt[(size_t)(n0 + i) * Kdim + (k0 + tx)] =
        __bfloat16_as_ushort(__float2bfloat16(tile[i][tx]));
  }
}

// ------------- main GEMM: C = X(fp32, fused cvt) @ Weff^T ----------------
__global__ void gemm_xf32(const float* __restrict__ X,
                          const uint16_t* __restrict__ Wt,
                          float* __restrict__ out) {
  __shared__ uint16_t As[BM * BK];  // 16 KB bf16, swizzled
  __shared__ uint16_t Bs[BN * BK];  // 16 KB bf16, swizzled

  const int t = threadIdx.x;
  const int wave = t >> 6, lane = t & 63;

  // XCD patch swizzle (R5-verified): xcd = lid&7 owns 8 M-blocks x 16 N-blocks.
  const int lid = blockIdx.x;                // 0..1023
  const int s   = lid >> 3;                  // 0..127 within XCD
  const int bx  = s & 15;                    // N-block 0..15
  const int by  = (lid & 7) * 8 + (s >> 4);  // M-block 0..63
  const int m0 = by * BM, n0 = bx * BN;

  const int wm = wave & 1, wn = wave >> 1;  // 2x2 wave grid, 64x64 each
  const int l15 = lane & 15, kg = lane >> 4;
  const int sw = l15 & 7;                   // frag-read row swizzle key

  // --- B staging (glds): chunk = 8 rows x 64 cols bf16 (1 KB), 16 chunks.
  const int r8 = lane >> 3;
  const int gcB = (lane & 7) ^ r8;          // swizzled global 16B col
  const uint16_t* Bg = Wt + (size_t)n0 * Kdim;

  // --- A staging (fused cvt): 16 lanes cover one row's 64 fp32 (256 B).
  const int g4 = lane >> 4;                 // 0..3
  const int cA = l15 >> 1;                  // A chunk 0..7
  const int halfA = l15 & 1;                // 8B half within chunk
  const float* Xg = X + (size_t)m0 * Kdim;

  f32x4 acc[4][4] = {};

  for (int kt = 0; kt < Kdim; kt += BK) {
    // A: fp32 loads first (longest latency) ...
    float4 av[8];
#pragma unroll
    for (int i = 0; i < 8; ++i) {
      const int row = wave * 32 + i * 4 + g4;
      av[i] = *reinterpret_cast<const float4*>(Xg + (size_t)row * Kdim + kt + l15 * 4);
    }
    // B: async global->LDS
#pragma unroll
    for (int c = 0; c < 4; ++c) {
      const int ch = wave * 4 + c;          // 0..15
      const int row = ch * 8 + r8;
      gload_lds16(Bg + (size_t)row * Kdim + kt + gcB * 8, &Bs[ch * 512]);
    }
    // A: cvt -> swizzled ds_write (R4-verified layout)
#pragma unroll
    for (int i = 0; i < 8; ++i) {
      const int row = wave * 32 + i * 4 + g4;
      const int p = cA ^ (row & 7);
      ushort4 o;
      o.x = __bfloat16_as_ushort(__float2bfloat16(av[i].x));
      o.y = __bfloat16_as_ushort(__float2bfloat16(av[i].y));
      o.z = __bfloat16_as_ushort(__float2bfloat16(av[i].z));
      o.w = __bfloat16_as_ushort(__float2bfloat16(av[i].w));
      *reinterpret_cast<uint2*>(&As[row * BK + p * 8 + halfA * 4]) =
          *reinterpret_cast<uint2*>(&o);
    }
    __syncthreads();  // drains vmcnt+lgkm -> tiles visible

#pragma unroll
    for (int s2 = 0; s2 < 2; ++s2) {        // two 16x16x32 k-steps per BK=64
      bf16x8 af[4], bfr[4];
      const int p = (s2 * 4 + kg) ^ sw;     // physical chunk for logical k-chunk
#pragma unroll
      for (int i = 0; i < 4; ++i) {
        const int ra = wm * 64 + i * 16 + l15;
        const int rb = wn * 64 + i * 16 + l15;
        af[i]  = *reinterpret_cast<const bf16x8*>(&As[ra * BK + p * 8]);
        bfr[i] = *reinterpret_cast<const bf16x8*>(&Bs[rb * BK + p * 8]);
      }
#pragma unroll
      for (int i = 0; i < 4; ++i)
#pragma unroll
        for (int j = 0; j < 4; ++j)
          acc[i][j] = __builtin_amdgcn_mfma_f32_16x16x32_bf16(af[i], bfr[j], acc[i][j], 0, 0, 0);
    }
    __syncthreads();  // before next stage overwrites tiles
  }

  // epilogue: C/D layout col = lane&15, row = (lane>>4)*4 + reg  [m89/m91]
#pragma unroll
  for (int i = 0; i < 4; ++i) {
    const int m_base = m0 + wm * 64 + i * 16 + kg * 4;
#pragma unroll
    for (int j = 0; j < 4; ++j) {
      const int n = n0 + wn * 64 + j * 16 + l15;
#pragma unroll
      for (int r = 0; r < 4; ++r) {
        out[(size_t)(m_base + r) * Ndim + n] = acc[i][j][r];
      }
    }
  }
}

extern "C" void kernel_launch(void* const* d_in, const int* in_sizes, int n_in,
                              void* d_out, int out_size, void* d_ws, size_t ws_size,
                              hipStream_t stream) {
  const float* x  = (const float*)d_in[0];  // [4,2048,2048]
  const float* W  = (const float*)d_in[1];  // [2048,16,128]
  const float* A  = (const float*)d_in[2];  // [2048,4]
  const float* Bk = (const float*)d_in[3];  // [4,16,128]
  float* out = (float*)d_out;               // [4,2048,16,128] fp32

  uint16_t* Wt = (uint16_t*)d_ws;           // [2048][2048] Weff^T bf16 (8 MB)

  // Weff^T build
  dim3 g1(Ndim / 64, Kdim / 64);  // 32 x 32
  prep_wt<<<g1, 256, 0, stream>>>(W, A, Bk, Wt);

  // fused cvt + GEMM (1D grid, XCD patch swizzle inside)
  gemm_xf32<<<(Ndim / BN) * (Mdim / BM), 256, 0, stream>>>(x, Wt, out);
}